// Round 7
// baseline (6019.525 us; speedup 1.0000x reference)
//
#include <hip/hip_runtime.h>
#include <cstdint>
#include <cstddef>

#define NB 8
#define NT 4096
#define NI 128
#define NH 256
#define NH2 512
#define NO 64
#define NSLICE 8
#define NJS 32
#define NTH 448

// workspace float offsets
#define OFF_MIR   0          // packed h: 16 teams * 2 parity * 256 u64 = 16384 floats
#define OFF_SC    16384      // scores: 8*4096 (softmax in-place -> also 'a')
#define OFF_CTX   49152      // ctx: 8*512
#define OFF_WT    53248      // w_att transposed: 512*512
#define OFF_PRED  315392     // pred: 8*4096*512
#define ZERO_FLOATS 53248    // zero mirror + scores + ctx

// ---------------------------------------------------------------------------
// Persistent bidirectional GRU recurrence. Transport = proven R2/R4 protocol:
// one u64 per h element = (step_tag<<32)|f32, RELAXED agent-scope atomics,
// parity dbuf. (R3/R5: same-XCD L2 fast paths lose on gfx950 — don't revisit.)
//
// R7 structure, 448 threads, wave-aligned roles (no poller/compute divergence):
//   wave 0   (0-31)   : gates -> h_{s+1}; publish first-thing; pred store
//   waves 1-4 (64-287): 3-deep staggered poll of the 224 remote words
//   w5+6a (320-415)   : full x-dots gx(s+1) under the poll wait (off the ring)
//   w6b  (416-447)    : stage x(t(s+2)) from regs; prefetch x(t(s+3))
//   bar ; B: h-dots only (tid<384) -> gh[pw] (+ pre-sum gx for r/z rows) ; bar
// grid = 128 WGs: wg = dir + 2*b + 16*slice (8 slices of 32 h-outputs).
// ---------------------------------------------------------------------------
__global__ __launch_bounds__(NTH, 1) void gru_rec(
    const float* __restrict__ x,
    const float* __restrict__ w_ih_f, const float* __restrict__ w_hh_f,
    const float* __restrict__ b_ih_f, const float* __restrict__ b_hh_f,
    const float* __restrict__ w_ih_b, const float* __restrict__ w_hh_b,
    const float* __restrict__ b_ih_b, const float* __restrict__ b_hh_b,
    unsigned long long* __restrict__ mir, float* __restrict__ pred)
{
    const int wg = blockIdx.x;
    const int dir = wg & 1;
    const int bb = (wg >> 1) & 7;
    const int slice = wg >> 4;
    const int tid = threadIdx.x;
    const int row = tid >> 2;      // B-role row (tid<384)
    const int q = tid & 3;         // B-role col quarter

    const float* wih = dir ? w_ih_b : w_ih_f;
    const float* whh = dir ? w_hh_b : w_hh_f;
    const float* bih = dir ? b_ih_b : b_ih_f;
    const float* bhh = dir ? b_hh_b : b_hh_f;

    __shared__ float h_lds[268];                    // c + 4*(c>>6) padding
    __shared__ __align__(16) float x_lds[2][128];   // broadcast reads: no pad
    __shared__ float gx_l[2][96], gh_l[2][96];      // parity double-buffered

    // ---- per-role one-time register state ----
    float wh[64];          // B-role h-weights (tid<384)
    float bh = 0.f;
    if (tid < 384) {
        const int grow = (row >> 5) * NH + slice * NJS + (row & 31);
        const float* p = whh + (size_t)grow * NH + q * 64;
        #pragma unroll
        for (int i = 0; i < 16; ++i) {
            float4 v = *(const float4*)(p + i * 4);
            wh[4*i] = v.x; wh[4*i+1] = v.y; wh[4*i+2] = v.z; wh[4*i+3] = v.w;
        }
        bh = bhh[grow];
    }
    float wiF[128];        // xdot-role full w_ih row (320<=tid<416)
    float biX = 0.f;
    const int rowX = tid - 320;    // 0..95 when xdot
    if (tid >= 320 && tid < 416) {
        const int growX = (rowX >> 5) * NH + slice * NJS + (rowX & 31);
        const float* p2 = wih + (size_t)growX * NI;
        #pragma unroll
        for (int i = 0; i < 32; ++i) {
            float4 v = *(const float4*)(p2 + i * 4);
            wiF[4*i] = v.x; wiF[4*i+1] = v.y; wiF[4*i+2] = v.z; wiF[4*i+3] = v.w;
        }
        biX = bih[growX];
    }

    unsigned long long* mb = mir + (size_t)(dir * NB + bb) * 2 * NH;  // [parity][256]
    const float* xb = x + (size_t)bb * NT * NI;
    float* predb = pred + (size_t)bb * NT * NH2 + dir * NH;

    // ---- prologue ----
    for (int i = tid; i < 268; i += NTH) h_lds[i] = 0.f;
    float hprev = 0.f;
    float4 xpre = make_float4(0.f, 0.f, 0.f, 0.f);
    const int si0 = (tid - 416) * 4;               // stage-role float offset
    if (tid >= 416) {
        const int t0 = dir ? (NT - 1) : 0;
        const int t1 = dir ? (NT - 2) : 1;
        const int t2 = dir ? (NT - 3) : 2;
        *(float4*)&x_lds[0][si0] = *(const float4*)(xb + (size_t)t0 * NI + si0);
        *(float4*)&x_lds[1][si0] = *(const float4*)(xb + (size_t)t1 * NI + si0);
        xpre = *(const float4*)(xb + (size_t)t2 * NI + si0);
    }
    __syncthreads();
    if (tid >= 320 && tid < 416) {   // gx(0) from x_lds[0]
        float a0 = 0.f, a1 = 0.f, a2 = 0.f, a3 = 0.f;
        const float* xp = x_lds[0];
        #pragma unroll
        for (int i = 0; i < 32; ++i) {
            a0 += wiF[i]      * xp[i];
            a1 += wiF[32 + i] * xp[32 + i];
            a2 += wiF[64 + i] * xp[64 + i];
            a3 += wiF[96 + i] * xp[96 + i];
        }
        gx_l[0][rowX] = ((a0 + a1) + (a2 + a3)) + biX;
    }
    __syncthreads();
    if (tid < 384 && q == 0) {       // gh(0): h_0 = 0 -> bh (+gx pre-sum r/z)
        float v = bh;
        if (row < 64) v += gx_l[0][row];
        gh_l[0][row] = v;
    }
    __syncthreads();

    for (int s = 0; s < NT; ++s) {
        const int t = dir ? (NT - 1 - s) : s;
        const int p = s & 1, pw = p ^ 1;

        // ---- Phase A ----
        if (tid < NJS) {
            // gates: r/z from pre-summed gh_l; n from split gx/gh
            const float sr = gh_l[p][tid];
            const float sz = gh_l[p][32 + tid];
            const float xn = gx_l[p][64 + tid];
            const float hn = gh_l[p][64 + tid];
            const float r = 1.f / (1.f + __expf(-sr));
            const float z = 1.f / (1.f + __expf(-sz));
            const float y = xn + r * hn;
            const float e2 = __expf(-2.f * y);
            const float n = (1.f - e2) / (1.f + e2);
            const float hnew = (1.f - z) * n + z * hprev;
            const int c = slice * NJS + tid;
            const unsigned long long pk =
                ((unsigned long long)(unsigned)(s + 1) << 32) |
                (unsigned long long)__float_as_uint(hnew);
            __hip_atomic_store(mb + (size_t)pw * NH + c, pk,
                               __ATOMIC_RELAXED, __HIP_MEMORY_SCOPE_AGENT);
            predb[(size_t)t * NH2 + c] = hnew;
            h_lds[c + 4 * (c >> 6)] = hnew;
            hprev = hnew;
        } else if (tid >= 64 && tid < 288) {
            if (s < NT - 1) {
                // 3-deep staggered poll: sampling interval ~ L/3
                const int idx = tid - 64;                       // 0..223
                const int rc = idx < slice * NJS ? idx : idx + NJS;
                const unsigned long long* ap = mb + (size_t)pw * NH + rc;
                const unsigned tag = (unsigned)(s + 1);
                unsigned long long v0 = __hip_atomic_load(ap, __ATOMIC_RELAXED, __HIP_MEMORY_SCOPE_AGENT);
                unsigned long long v1 = __hip_atomic_load(ap, __ATOMIC_RELAXED, __HIP_MEMORY_SCOPE_AGENT);
                unsigned long long v2 = __hip_atomic_load(ap, __ATOMIC_RELAXED, __HIP_MEMORY_SCOPE_AGENT);
                while ((unsigned)(v0 >> 32) != tag) {
                    v0 = v1; v1 = v2;
                    v2 = __hip_atomic_load(ap, __ATOMIC_RELAXED, __HIP_MEMORY_SCOPE_AGENT);
                }
                h_lds[rc + 4 * (rc >> 6)] = __uint_as_float((unsigned)v0);
            }
        } else if (tid >= 416) {
            // stage x(t(s+2)) from regs; prefetch x(t(s+3))
            *(float4*)&x_lds[p][si0] = xpre;
            int tn = dir ? (NT - 4 - s) : (s + 3);
            tn = tn < 0 ? 0 : (tn >= NT ? NT - 1 : tn);
            xpre = *(const float4*)(xb + (size_t)tn * NI + si0);
        } else if (tid >= 320) {
            // full x-dot for gx(s+1), hidden under the poll wait
            if (s + 1 < NT) {
                float a0 = 0.f, a1 = 0.f, a2 = 0.f, a3 = 0.f;
                const float* xp = x_lds[pw];
                #pragma unroll
                for (int i = 0; i < 32; ++i) {
                    a0 += wiF[i]      * xp[i];
                    a1 += wiF[32 + i] * xp[32 + i];
                    a2 += wiF[64 + i] * xp[64 + i];
                    a3 += wiF[96 + i] * xp[96 + i];
                }
                gx_l[pw][rowX] = ((a0 + a1) + (a2 + a3)) + biX;
            }
        }
        __syncthreads();

        // ---- Phase B: h-dots only -> gh[pw] ----
        if (s < NT - 1) {
            if (tid < 384) {
                float ah0 = 0.f, ah1 = 0.f, ah2 = 0.f, ah3 = 0.f;
                const float* hp = h_lds + q * 68;
                #pragma unroll
                for (int i = 0; i < 16; ++i) {
                    ah0 += wh[i]      * hp[i];
                    ah1 += wh[16 + i] * hp[16 + i];
                    ah2 += wh[32 + i] * hp[32 + i];
                    ah3 += wh[48 + i] * hp[48 + i];
                }
                float ah = (ah0 + ah1) + (ah2 + ah3);
                ah += __shfl_xor(ah, 1); ah += __shfl_xor(ah, 2);
                if (q == 0) {
                    float v = ah + bh;
                    if (row < 64) v += gx_l[pw][row];   // pre-sum for r/z gates
                    gh_l[pw][row] = v;
                }
            }
            __syncthreads();
        }
    }
}

// ---------------------------------------------------------------------------
// w_att transpose: wT[k][h] = w_att[h][k]
// ---------------------------------------------------------------------------
__global__ void transpose_watt(const float* __restrict__ w_att, float* __restrict__ wT) {
    const int n = blockIdx.x * 256 + threadIdx.x;   // 0..262143
    const int k = n >> 9, h = n & 511;
    wT[n] = w_att[h * NH2 + k];
}

// ---------------------------------------------------------------------------
// Fused scores = sum_k tanh(pred @ w_att)[.,k] * v[k], tiled 64t x 64k,
// K(=h)=512 chunked by 64 through LDS. Partial scores via atomicAdd.
// ---------------------------------------------------------------------------
__global__ __launch_bounds__(256) void scores_gemm(
    const float* __restrict__ pred, const float* __restrict__ wT,
    const float* __restrict__ v_att, float* __restrict__ scores)
{
    const int tt = blockIdx.x, kt = blockIdx.y, bb = blockIdx.z;
    const int tid = threadIdx.x;
    const int tx = tid & 15;   // k micro index
    const int ty = tid >> 4;   // t micro index
    __shared__ float As[64][68];   // [t][h]
    __shared__ float Bs[64][68];   // [h][k]
    __shared__ float red[64][17];
    float acc[4][4] = {{0.f}};
    const int t0 = tt * 64, k0 = kt * 64;
    const float* pb = pred + ((size_t)bb * NT + t0) * NH2;

    for (int hc = 0; hc < NH2; hc += 64) {
        #pragma unroll
        for (int r = 0; r < 4; ++r) {
            const int idx = tid + 256 * r;
            const int tr = idx >> 4;           // row 0..63
            const int c4 = (idx & 15) * 4;     // col 0..60
            float4 a = *(const float4*)(pb + (size_t)tr * NH2 + hc + c4);
            *(float4*)&As[tr][c4] = a;
            float4 w = *(const float4*)(wT + (size_t)(k0 + tr) * NH2 + hc + c4);
            Bs[c4 + 0][tr] = w.x; Bs[c4 + 1][tr] = w.y;
            Bs[c4 + 2][tr] = w.z; Bs[c4 + 3][tr] = w.w;
        }
        __syncthreads();
        #pragma unroll
        for (int h = 0; h < 64; ++h) {
            const float a0 = As[ty*4+0][h], a1 = As[ty*4+1][h];
            const float a2 = As[ty*4+2][h], a3 = As[ty*4+3][h];
            const float4 bv = *(const float4*)&Bs[h][tx*4];
            acc[0][0] += a0*bv.x; acc[0][1] += a0*bv.y; acc[0][2] += a0*bv.z; acc[0][3] += a0*bv.w;
            acc[1][0] += a1*bv.x; acc[1][1] += a1*bv.y; acc[1][2] += a1*bv.z; acc[1][3] += a1*bv.w;
            acc[2][0] += a2*bv.x; acc[2][1] += a2*bv.y; acc[2][2] += a2*bv.z; acc[2][3] += a2*bv.w;
            acc[3][0] += a3*bv.x; acc[3][1] += a3*bv.y; acc[3][2] += a3*bv.z; acc[3][3] += a3*bv.w;
        }
        __syncthreads();
    }
    const float4 vv = *(const float4*)(v_att + k0 + tx * 4);
    #pragma unroll
    for (int i = 0; i < 4; ++i) {
        const float p = tanhf(acc[i][0]) * vv.x + tanhf(acc[i][1]) * vv.y
                      + tanhf(acc[i][2]) * vv.z + tanhf(acc[i][3]) * vv.w;
        red[ty*4+i][tx] = p;
    }
    __syncthreads();
    if (tid < 64) {
        float ssum = 0.f;
        #pragma unroll
        for (int xx = 0; xx < 16; ++xx) ssum += red[tid][xx];
        atomicAdd(&scores[bb * NT + t0 + tid], ssum);
    }
}

// ---------------------------------------------------------------------------
// softmax over T per batch (in-place)
// ---------------------------------------------------------------------------
__global__ void softmax_t(float* __restrict__ scores) {
    const int bb = blockIdx.x;
    const int tid = threadIdx.x;   // 256
    __shared__ float red[256];
    float m = -1e30f;
    for (int t = tid; t < NT; t += 256) m = fmaxf(m, scores[bb*NT + t]);
    red[tid] = m; __syncthreads();
    for (int s2 = 128; s2; s2 >>= 1) { if (tid < s2) red[tid] = fmaxf(red[tid], red[tid+s2]); __syncthreads(); }
    m = red[0]; __syncthreads();
    float sum = 0.f;
    for (int t = tid; t < NT; t += 256) sum += expf(scores[bb*NT + t] - m);
    red[tid] = sum; __syncthreads();
    for (int s2 = 128; s2; s2 >>= 1) { if (tid < s2) red[tid] += red[tid+s2]; __syncthreads(); }
    const float inv = 1.f / red[0];
    for (int t = tid; t < NT; t += 256) scores[bb*NT + t] = expf(scores[bb*NT + t] - m) * inv;
}

// ---------------------------------------------------------------------------
// ctx[b][h] = sum_t a[b][t] * pred[b][t][h]  (partial per t-chunk, atomicAdd)
// ---------------------------------------------------------------------------
__global__ void ctx_kernel(const float* __restrict__ pred, const float* __restrict__ a,
                           float* __restrict__ ctx) {
    const int bb = blockIdx.x, ch = blockIdx.y;   // 32 chunks of 128 t
    const int tid = threadIdx.x;                  // 256
    const int t0 = ch * 128;
    float acc0 = 0.f, acc1 = 0.f;
    for (int t = 0; t < 128; ++t) {
        const float av = a[bb*NT + t0 + t];
        const float* p = pred + ((size_t)bb * NT + t0 + t) * NH2;
        acc0 += av * p[tid];
        acc1 += av * p[tid + 256];
    }
    atomicAdd(&ctx[bb*NH2 + tid], acc0);
    atomicAdd(&ctx[bb*NH2 + tid + 256], acc1);
}

// ---------------------------------------------------------------------------
// logits = ctx @ w_lin^T + b_lin ; out = softmax(logits) per batch.
// ---------------------------------------------------------------------------
__global__ __launch_bounds__(512) void final_kernel(
    const float* __restrict__ ctx, const float* __restrict__ w_lin,
    const float* __restrict__ b_lin, float* __restrict__ out)
{
    const int tid = threadIdx.x;
    const int bb = tid >> 6, o = tid & 63;
    __shared__ float cl[NB][NH2];
    for (int i = tid; i < NB * NH2; i += 512) cl[i >> 9][i & 511] = ctx[i];
    __syncthreads();
    float acc = b_lin[o];
    for (int h = 0; h < NH2; h += 4) {
        const float4 w = *(const float4*)&w_lin[o * NH2 + h];
        acc += cl[bb][h]*w.x + cl[bb][h+1]*w.y + cl[bb][h+2]*w.z + cl[bb][h+3]*w.w;
    }
    float m = acc;
    for (int off = 32; off; off >>= 1) m = fmaxf(m, __shfl_xor(m, off));
    const float e = expf(acc - m);
    float ssum = e;
    for (int off = 32; off; off >>= 1) ssum += __shfl_xor(ssum, off);
    out[tid] = e / ssum;
}

extern "C" void kernel_launch(void* const* d_in, const int* in_sizes, int n_in,
                              void* d_out, int out_size, void* d_ws, size_t ws_size,
                              hipStream_t stream) {
    (void)in_sizes; (void)n_in; (void)out_size; (void)ws_size;
    const float* x      = (const float*)d_in[0];
    const float* w_ih_f = (const float*)d_in[1];
    const float* w_hh_f = (const float*)d_in[2];
    const float* b_ih_f = (const float*)d_in[3];
    const float* b_hh_f = (const float*)d_in[4];
    const float* w_ih_b = (const float*)d_in[5];
    const float* w_hh_b = (const float*)d_in[6];
    const float* b_ih_b = (const float*)d_in[7];
    const float* b_hh_b = (const float*)d_in[8];
    const float* w_att  = (const float*)d_in[9];
    const float* v_att  = (const float*)d_in[10];
    const float* w_lin  = (const float*)d_in[11];
    const float* b_lin  = (const float*)d_in[12];

    float* ws     = (float*)d_ws;
    unsigned long long* mir = (unsigned long long*)(ws + OFF_MIR);
    float* scores = ws + OFF_SC;     // softmax in-place -> also 'a'
    float* ctx    = ws + OFF_CTX;
    float* wT     = ws + OFF_WT;
    float* pred   = ws + OFF_PRED;
    float* out    = (float*)d_out;

    hipMemsetAsync(d_ws, 0, (size_t)ZERO_FLOATS * sizeof(float), stream);
    hipLaunchKernelGGL(transpose_watt, dim3(1024), dim3(256), 0, stream, w_att, wT);
    hipLaunchKernelGGL(gru_rec, dim3(128), dim3(NTH), 0, stream,
                       x, w_ih_f, w_hh_f, b_ih_f, b_hh_f,
                       w_ih_b, w_hh_b, b_ih_b, b_hh_b, mir, pred);
    hipLaunchKernelGGL(scores_gemm, dim3(64, 8, 8), dim3(256), 0, stream,
                       pred, wT, v_att, scores);
    hipLaunchKernelGGL(softmax_t, dim3(8), dim3(256), 0, stream, scores);
    hipLaunchKernelGGL(ctx_kernel, dim3(8, 32), dim3(256), 0, stream, pred, scores, ctx);
    hipLaunchKernelGGL(final_kernel, dim3(1), dim3(512), 0, stream, ctx, w_lin, b_lin, out);
}